// Round 8
// baseline (256.290 us; speedup 1.0000x reference)
//
#include <hip/hip_runtime.h>

#define SS 2048
#define DD 64
#define QB 64       // q rows per b_pass block
#define KVB 64      // kv rows per staged tile
#define NT (SS / KVB)

typedef unsigned short ushort_t;
typedef __attribute__((ext_vector_type(4)))  float f32x4;
typedef __attribute__((ext_vector_type(16))) float f32x16;
typedef __attribute__((ext_vector_type(8)))  short bf16x8;
typedef __attribute__((ext_vector_type(2)))  unsigned int u32x2;

static __device__ __forceinline__ unsigned short f2bf(float f) {
    unsigned u = __builtin_bit_cast(unsigned, f);
    u += 0x7FFFu + ((u >> 16) & 1u);
    return (unsigned short)(u >> 16);
}

static __device__ __forceinline__ f32x16 zero16() {
    f32x16 z;
#pragma unroll
    for (int i = 0; i < 16; ++i) z[i] = 0.f;
    return z;
}

union PFrag { bf16x8 v; unsigned w[4]; };

#define GLL16(src, dst) \
    __builtin_amdgcn_global_load_lds((const __attribute__((address_space(1))) void*)(src), \
                                     (__attribute__((address_space(3))) void*)(dst), 16, 0, 0)

// ---------------- prologue: fp32 -> bf16 ----------------
__global__ void cvt_bf16(const float* __restrict__ src, ushort_t* __restrict__ dst,
                         int n8, float scale)
{
    int i = blockIdx.x * blockDim.x + threadIdx.x;
    if (i >= n8) return;
    f32x4 a = ((const f32x4*)src)[2 * i];
    f32x4 b = ((const f32x4*)src)[2 * i + 1];
    bf16x8 o;
#pragma unroll
    for (int j = 0; j < 4; ++j) o[j] = (short)f2bf(a[j] * scale);
#pragma unroll
    for (int j = 0; j < 4; ++j) o[4 + j] = (short)f2bf(b[j] * scale);
    ((bf16x8*)dst)[i] = o;
}

// ---------------- prologue: V [h][kv][d] fp32 -> V^T [h][d][kv] bf16 ----------------
__global__ void transposeV(const float* __restrict__ V, ushort_t* __restrict__ Vt)
{
    __shared__ float tile[64][65];
    const int tid = threadIdx.x;
    const int hh = blockIdx.x >> 5;
    const int kt = blockIdx.x & 31;

#pragma unroll
    for (int it = 0; it < 4; ++it) {
        int m = it * 256 + tid;
        int r = m >> 4, c4 = m & 15;
        f32x4 v = *(const f32x4*)(V + ((size_t)(hh * SS + kt * 64 + r)) * DD + c4 * 4);
#pragma unroll
        for (int j = 0; j < 4; ++j) tile[r][c4 * 4 + j] = v[j];
    }
    __syncthreads();
#pragma unroll
    for (int it = 0; it < 2; ++it) {
        int m = it * 256 + tid;
        int d = m >> 3, c8 = m & 7;
        bf16x8 o;
#pragma unroll
        for (int j = 0; j < 8; ++j) o[j] = (short)f2bf(tile[c8 * 8 + j][d]);
        *(bf16x8*)(Vt + ((size_t)hh * DD + d) * SS + kt * 64 + c8 * 8) = o;
    }
}

// ---------------- kernel 1: denominators only (R3-proven structure) ----------------
__global__ __launch_bounds__(256, 4)
void l_pass(const float* __restrict__ gQ, const ushort_t* __restrict__ Kbf,
            float* __restrict__ wsR)
{
    __shared__ float lsm[4][32];

    const int tid  = threadIdx.x;
    const int lane = tid & 63;
    const int wave = tid >> 6;
    const int lo5  = lane & 31;
    const int hi   = lane >> 5;

    const int bid  = blockIdx.x;
    const int wg   = (bid & 7) * 256 + (bid >> 3);   // XCD-contiguous
    const int head = wg >> 6;
    const int q0b  = (wg & 63) * 32;

    const float*    Qh = gQ  + (size_t)head * SS * DD;
    const ushort_t* Kh = Kbf + (size_t)head * SS * DD;

    const float SCALE = 0.125f * 1.44269504088896340736f;

    const int qrow = q0b + lo5;
    bf16x8 qf[4];
#pragma unroll
    for (int ks = 0; ks < 4; ++ks) {
        const float* qp = Qh + (size_t)qrow * DD + ks * 16 + hi * 8;
        f32x4 a = *(const f32x4*)(qp);
        f32x4 b = *(const f32x4*)(qp + 4);
        bf16x8 o;
#pragma unroll
        for (int j = 0; j < 4; ++j) o[j] = (short)f2bf(a[j] * SCALE);
#pragma unroll
        for (int j = 0; j < 4; ++j) o[4 + j] = (short)f2bf(b[j] * SCALE);
        qf[ks] = o;
    }

    const int kv_base = wave * 512;
    float ls0 = 0.f, ls1 = 0.f;
#pragma unroll 2
    for (int t = 0; t < 8; ++t) {
        int kv0 = kv_base + t * 64;
#pragma unroll
        for (int sub = 0; sub < 2; ++sub) {
            f32x16 acc = zero16();
            const ushort_t* kp = Kh + (size_t)(kv0 + sub * 32 + lo5) * DD + hi * 8;
#pragma unroll
            for (int ks = 0; ks < 4; ++ks) {
                bf16x8 kf = *(const bf16x8*)(kp + ks * 16);
                acc = __builtin_amdgcn_mfma_f32_32x32x16_bf16(kf, qf[ks], acc, 0, 0, 0);
            }
#pragma unroll
            for (int r = 0; r < 16; r += 2) {
                ls0 += __builtin_exp2f(acc[r]);
                ls1 += __builtin_exp2f(acc[r + 1]);
            }
        }
    }
    float lsum = ls0 + ls1;
    lsum += __shfl_xor(lsum, 32);
    lsm[wave][lo5] = lsum;
    __syncthreads();
    if (tid < 32) {
        float l = lsm[0][tid] + lsm[1][tid] + lsm[2][tid] + lsm[3][tid];
        wsR[(size_t)head * SS + q0b + tid] = 1.0f / l;
    }
}

// ---------------- kernel 2: single-pass scores + P write + PV (R6 pass B) ----------------
__global__ __launch_bounds__(256, 4)
void b_pass(const float* __restrict__ gQ, const ushort_t* __restrict__ Kbf,
            const ushort_t* __restrict__ Vtbf, const float* __restrict__ wsR,
            float* __restrict__ gO, float* __restrict__ gP)
{
    __shared__ __attribute__((aligned(16))) char shraw[33792]; // union: stage / osm
    ushort_t* stage = (ushort_t*)shraw;   // [2 buf][ K:4096 | V:4096 ] elems
    float*    osm   = (float*)shraw;      // [4][64][33] after main loop

    const int tid  = threadIdx.x;
    const int lane = tid & 63;
    const int wave = tid >> 6;
    const int lo5  = lane & 31;
    const int hi   = lane >> 5;
    const int qs   = wave >> 1;          // q sub-tile (0,1)
    const int sub  = wave & 1;           // kv sub within 64-tile (0,1)

    const int bid  = blockIdx.x;
    const int wg   = (bid & 7) * 128 + (bid >> 3);  // XCD-contiguous
    const int head = wg >> 5;
    const int q0b  = (wg & 31) * QB;

    const float*    Qh = gQ   + (size_t)head * SS * DD;
    const ushort_t* Kh = Kbf  + (size_t)head * SS * DD;
    const ushort_t* Vh = Vtbf + (size_t)head * DD * SS;   // [d][kv]
    float* Oh = gO + (size_t)head * SS * DD;
    float* Ph = gP + (size_t)head * SS * SS;

    const float SCALE = 0.125f * 1.44269504088896340736f;

    const int qrow = q0b + qs * 32 + lo5;
    bf16x8 qf[4];
#pragma unroll
    for (int ks = 0; ks < 4; ++ks) {
        const float* qp = Qh + (size_t)qrow * DD + ks * 16 + hi * 8;
        f32x4 a = *(const f32x4*)(qp);
        f32x4 b = *(const f32x4*)(qp + 4);
        bf16x8 o;
#pragma unroll
        for (int j = 0; j < 4; ++j) o[j] = (short)f2bf(a[j] * SCALE);
#pragma unroll
        for (int j = 0; j < 4; ++j) o[4 + j] = (short)f2bf(b[j] * SCALE);
        qf[ks] = o;
    }
    const float rinv = wsR[(size_t)head * SS + qrow];

    // staging addresses (source pre-swizzled, LDS dest linear)
    const int lgrp = lane >> 3;
    const int lchk = (lane & 7) ^ lgrp;
    const ushort_t* srcK[2]; const ushort_t* srcV[2];
#pragma unroll
    for (int j = 0; j < 2; ++j) {
        int W = wave * 2 + j;
        srcK[j] = Kh + (size_t)(W * 8 + lgrp) * DD + lchk * 8;
        srcV[j] = Vh + (size_t)(W * 8 + lgrp) * SS + lchk * 8;
    }
    const int kvl = sub * 32 + lo5;

    f32x16 o0 = zero16(), o1 = zero16();
    float* prow_base = Ph + (size_t)qrow * SS;

#pragma unroll
    for (int j = 0; j < 2; ++j) {
        GLL16(srcK[j], stage + (wave * 2 + j) * 512);
        GLL16(srcV[j], stage + 4096 + (wave * 2 + j) * 512);
    }
    __syncthreads();

    for (int t = 0; t < NT; ++t) {
        const int buf = t & 1;
        if (t + 1 < NT) {
#pragma unroll
            for (int j = 0; j < 2; ++j) {
                GLL16(srcK[j] + (size_t)(t + 1) * KVB * DD,
                      stage + (buf ^ 1) * 8192 + (wave * 2 + j) * 512);
                GLL16(srcV[j] + (size_t)(t + 1) * KVB,
                      stage + (buf ^ 1) * 8192 + 4096 + (wave * 2 + j) * 512);
            }
        }
        const ushort_t* Ksb = stage + buf * 8192;
        const ushort_t* Vtb = Ksb + 4096;

        f32x16 acc = zero16();
#pragma unroll
        for (int ks = 0; ks < 4; ++ks) {
            bf16x8 kf = *(const bf16x8*)(Ksb + kvl * 64 + ((((ks * 2) + hi) ^ (kvl & 7)) << 3));
            acc = __builtin_amdgcn_mfma_f32_32x32x16_bf16(kf, qf[ks], acc, 0, 0, 0);
        }
        float pr[16];
#pragma unroll
        for (int r = 0; r < 16; ++r) pr[r] = __builtin_exp2f(acc[r]);

        float* prow = prow_base + t * KVB + sub * 32;
#pragma unroll
        for (int g = 0; g < 4; ++g) {
            f32x4 st = { pr[4*g+0] * rinv, pr[4*g+1] * rinv, pr[4*g+2] * rinv, pr[4*g+3] * rinv };
            *(f32x4*)(prow + g * 8 + hi * 4) = st;
        }

        unsigned u[8];
#pragma unroll
        for (int j = 0; j < 8; ++j)
            u[j] = (unsigned)f2bf(pr[2*j]) | ((unsigned)f2bf(pr[2*j+1]) << 16);

        unsigned s0 = __shfl_xor(u[0], 32), s1 = __shfl_xor(u[1], 32);
        unsigned s2 = __shfl_xor(u[2], 32), s3 = __shfl_xor(u[3], 32);
        unsigned s4 = __shfl_xor(u[4], 32), s5 = __shfl_xor(u[5], 32);
        unsigned s6 = __shfl_xor(u[6], 32), s7 = __shfl_xor(u[7], 32);
        PFrag pf0, pf1;
        pf0.w[0] = hi ? s2 : u[0];  pf0.w[1] = hi ? s3 : u[1];
        pf0.w[2] = hi ? u[2] : s0;  pf0.w[3] = hi ? u[3] : s1;
        pf1.w[0] = hi ? s6 : u[4];  pf1.w[1] = hi ? s7 : u[5];
        pf1.w[2] = hi ? u[6] : s4;  pf1.w[3] = hi ? u[7] : s5;

#pragma unroll
        for (int dt = 0; dt < 2; ++dt) {
            int drow = dt * 32 + lo5;
            int c0 = ((sub * 4) + 0 + hi) ^ (drow & 7);
            int c1 = ((sub * 4) + 2 + hi) ^ (drow & 7);
            bf16x8 vf0 = *(const bf16x8*)(Vtb + drow * 64 + (c0 << 3));
            bf16x8 vf1 = *(const bf16x8*)(Vtb + drow * 64 + (c1 << 3));
            f32x16& od = dt ? o1 : o0;
            od = __builtin_amdgcn_mfma_f32_32x32x16_bf16(vf0, pf0.v, od, 0, 0, 0);
            od = __builtin_amdgcn_mfma_f32_32x32x16_bf16(vf1, pf1.v, od, 0, 0, 0);
        }

        __syncthreads();
    }

    // epilogue: 2-way O reduce through reused LDS
#pragma unroll
    for (int dt = 0; dt < 2; ++dt) {
        const f32x16& od = dt ? o1 : o0;
#pragma unroll
        for (int g = 0; g < 4; ++g) {
#pragma unroll
            for (int j = 0; j < 4; ++j) {
                int d = dt * 32 + g * 8 + hi * 4 + j;
                osm[(wave * 64 + d) * 33 + lo5] = od[4 * g + j];
            }
        }
    }
    __syncthreads();
    {
        const int p  = tid >> 7;
        const int q  = (tid >> 2) & 31;
        const int d0 = (tid & 3) * 16;
        const float rq = wsR[(size_t)head * SS + q0b + p * 32 + q];
        float* op = Oh + (size_t)(q0b + p * 32 + q) * DD + d0;
#pragma unroll
        for (int v4 = 0; v4 < 4; ++v4) {
            f32x4 st;
#pragma unroll
            for (int j = 0; j < 4; ++j) {
                int d = d0 + v4 * 4 + j;
                st[j] = (osm[((2 * p) * 64 + d) * 33 + q] +
                         osm[((2 * p + 1) * 64 + d) * 33 + q]) * rq;
            }
            *(f32x4*)(op + v4 * 4) = st;
        }
    }
}

// ================= fallback (no-ws path) =================
__global__ __launch_bounds__(256, 2)
void attn_fused(const float* __restrict__ gQ, const float* __restrict__ gK,
                const float* __restrict__ gV, float* __restrict__ gO,
                float* __restrict__ gP)
{
    __shared__ unsigned short Qs[128 * DD];
    __shared__ unsigned short Ks[64 * DD];
    __shared__ unsigned short Vt[DD * 64];

    const int tid  = threadIdx.x;
    const int lane = tid & 63;
    const int wave = tid >> 6;
    const int lo5  = lane & 31;
    const int hi   = lane >> 5;

    const int head = blockIdx.x >> 4;
    const int q0b  = (blockIdx.x & 15) * 128;

    const float* Qh = gQ + (size_t)head * SS * DD;
    const float* Kh = gK + (size_t)head * SS * DD;
    const float* Vh = gV + (size_t)head * SS * DD;
    float* Oh = gO + (size_t)head * SS * DD;
    float* Ph = gP + (size_t)head * SS * SS;

    const float SCALE = 0.125f * 1.44269504088896340736f;

#pragma unroll
    for (int it = 0; it < 8; ++it) {
        int m = it * 256 + tid;
        int q = m >> 4, d4 = m & 15;
        f32x4 v = *(const f32x4*)(Qh + (size_t)(q0b + q) * DD + d4 * 4);
        unsigned a = (unsigned)f2bf(v.x * SCALE) | ((unsigned)f2bf(v.y * SCALE) << 16);
        unsigned b = (unsigned)f2bf(v.z * SCALE) | ((unsigned)f2bf(v.w * SCALE) << 16);
        u32x2 w; w.x = a; w.y = b;
        *(u32x2*)(Qs + q * 64 + d4 * 4) = w;
    }
    __syncthreads();

    const int qrow = wave * 32 + lo5;
    bf16x8 qf[4];
#pragma unroll
    for (int ks = 0; ks < 4; ++ks)
        qf[ks] = *(const bf16x8*)(Qs + qrow * 64 + ks * 16 + hi * 8);

    auto stageK = [&](int kv0) {
#pragma unroll
        for (int it = 0; it < 4; ++it) {
            int m = it * 256 + tid;
            int kv = m >> 4, d4 = m & 15;
            f32x4 v = *(const f32x4*)(Kh + (size_t)(kv0 + kv) * DD + d4 * 4);
            unsigned a = (unsigned)f2bf(v.x) | ((unsigned)f2bf(v.y) << 16);
            unsigned b = (unsigned)f2bf(v.z) | ((unsigned)f2bf(v.w) << 16);
            int c16 = (d4 >> 1) ^ (kv & 7);
            u32x2 w; w.x = a; w.y = b;
            *(u32x2*)(Ks + kv * 64 + c16 * 8 + (d4 & 1) * 4) = w;
        }
    };
    auto stageV = [&](int kv0) {
#pragma unroll
        for (int it = 0; it < 2; ++it) {
            int m = it * 256 + tid;
            int kv2 = m >> 4, d4 = m & 15;
            const float* p0 = Vh + (size_t)(kv0 + kv2 * 2) * DD + d4 * 4;
            f32x4 v0 = *(const f32x4*)(p0);
            f32x4 v1 = *(const f32x4*)(p0 + DD);
#pragma unroll
            for (int c = 0; c < 4; ++c) {
                int d = d4 * 4 + c;
                unsigned u = (unsigned)f2bf(v0[c]) | ((unsigned)f2bf(v1[c]) << 16);
                int c16 = (kv2 >> 2) ^ (d & 7);
                *(unsigned*)(Vt + d * 64 + c16 * 8 + (kv2 & 3) * 2) = u;
            }
        }
    };

    float m_run = -1e30f, l_run = 0.f;
    for (int kv0 = 0; kv0 < SS; kv0 += 64) {
        __syncthreads();
        stageK(kv0);
        __syncthreads();
#pragma unroll
        for (int sub = 0; sub < 2; ++sub) {
            f32x16 acc = zero16();
            int kvl = sub * 32 + lo5;
#pragma unroll
            for (int ks = 0; ks < 4; ++ks) {
                bf16x8 kf = *(const bf16x8*)(Ks + kvl * 64 + ((((ks * 2) + hi) ^ (kvl & 7)) << 3));
                acc = __builtin_amdgcn_mfma_f32_32x32x16_bf16(kf, qf[ks], acc, 0, 0, 0);
            }
            float tm = acc[0];
#pragma unroll
            for (int r = 1; r < 16; ++r) tm = fmaxf(tm, acc[r]);
            float mn = fmaxf(m_run, tm);
            float sum = 0.f;
#pragma unroll
            for (int r = 0; r < 16; ++r) sum += __builtin_exp2f(acc[r] - mn);
            l_run = l_run * __builtin_exp2f(m_run - mn) + sum;
            m_run = mn;
        }
    }
    {
        float mo = __shfl_xor(m_run, 32);
        float mf = fmaxf(m_run, mo);
        float la = l_run * __builtin_exp2f(m_run - mf);
        float lb = __shfl_xor(la, 32);
        l_run = la + lb;
        m_run = mf;
    }
    const float rinv = 1.0f / l_run;

    f32x16 o0 = zero16(), o1 = zero16();
    const int qg = q0b + wave * 32 + lo5;
    float* prow_base = Ph + (size_t)qg * SS;

    for (int kv0 = 0; kv0 < SS; kv0 += 64) {
        __syncthreads();
        stageK(kv0);
        stageV(kv0);
        __syncthreads();
#pragma unroll
        for (int sub = 0; sub < 2; ++sub) {
            f32x16 acc = zero16();
            int kvl = sub * 32 + lo5;
#pragma unroll
            for (int ks = 0; ks < 4; ++ks) {
                bf16x8 kf = *(const bf16x8*)(Ks + kvl * 64 + ((((ks * 2) + hi) ^ (kvl & 7)) << 3));
                acc = __builtin_amdgcn_mfma_f32_32x32x16_bf16(kf, qf[ks], acc, 0, 0, 0);
            }
            float pr[16];
#pragma unroll
            for (int r = 0; r < 16; ++r) pr[r] = __builtin_exp2f(acc[r] - m_run);

            float* prow = prow_base + kv0 + sub * 32;
#pragma unroll
            for (int g = 0; g < 4; ++g) {
                f32x4 st = { pr[4*g+0] * rinv, pr[4*g+1] * rinv, pr[4*g+2] * rinv, pr[4*g+3] * rinv };
                *(f32x4*)(prow + g * 8 + hi * 4) = st;
            }

            unsigned u[8];
#pragma unroll
            for (int j = 0; j < 8; ++j)
                u[j] = (unsigned)f2bf(pr[2*j]) | ((unsigned)f2bf(pr[2*j+1]) << 16);

            unsigned s0 = __shfl_xor(u[0], 32), s1 = __shfl_xor(u[1], 32);
            unsigned s2 = __shfl_xor(u[2], 32), s3 = __shfl_xor(u[3], 32);
            unsigned s4 = __shfl_xor(u[4], 32), s5 = __shfl_xor(u[5], 32);
            unsigned s6 = __shfl_xor(u[6], 32), s7 = __shfl_xor(u[7], 32);
            PFrag pf0, pf1;
            pf0.w[0] = hi ? s2 : u[0];  pf0.w[1] = hi ? s3 : u[1];
            pf0.w[2] = hi ? u[2] : s0;  pf0.w[3] = hi ? u[3] : s1;
            pf1.w[0] = hi ? s6 : u[4];  pf1.w[1] = hi ? s7 : u[5];
            pf1.w[2] = hi ? u[6] : s4;  pf1.w[3] = hi ? u[7] : s5;

#pragma unroll
            for (int dt = 0; dt < 2; ++dt) {
                int drow = dt * 32 + lo5;
                int c0 = ((sub * 4) + 0 + hi) ^ (drow & 7);
                int c1 = ((sub * 4) + 2 + hi) ^ (drow & 7);
                bf16x8 vf0 = *(const bf16x8*)(Vt + drow * 64 + (c0 << 3));
                bf16x8 vf1 = *(const bf16x8*)(Vt + drow * 64 + (c1 << 3));
                f32x16& od = dt ? o1 : o0;
                od = __builtin_amdgcn_mfma_f32_32x32x16_bf16(vf0, pf0.v, od, 0, 0, 0);
                od = __builtin_amdgcn_mfma_f32_32x32x16_bf16(vf1, pf1.v, od, 0, 0, 0);
            }
        }
    }

    float* orow = Oh + (size_t)qg * DD;
#pragma unroll
    for (int dt = 0; dt < 2; ++dt) {
        const f32x16& od = dt ? o1 : o0;
#pragma unroll
        for (int g = 0; g < 4; ++g) {
            f32x4 st = { od[4*g+0] * rinv, od[4*g+1] * rinv, od[4*g+2] * rinv, od[4*g+3] * rinv };
            *(f32x4*)(orow + dt * 32 + g * 8 + hi * 4) = st;
        }
    }
}

extern "C" void kernel_launch(void* const* d_in, const int* in_sizes, int n_in,
                              void* d_out, int out_size, void* d_ws, size_t ws_size,
                              hipStream_t stream) {
    const float* Q = (const float*)d_in[0];
    const float* K = (const float*)d_in[1];
    const float* V = (const float*)d_in[2];
    float* O = (float*)d_out;
    float* P = O + (size_t)2 * 16 * SS * DD;

    const size_t HD = (size_t)32 * SS * DD;           // elems per tensor
    const size_t RN = (size_t)32 * SS;                // rinv elems
    const size_t need = 2 * HD * sizeof(ushort_t) + RN * sizeof(float);  // ~17.0 MB

    if (ws_size >= need) {
        ushort_t* Kbf  = (ushort_t*)d_ws;
        ushort_t* Vtbf = Kbf + HD;
        float*    wsR  = (float*)(Vtbf + HD);
        int n8 = (int)(HD / 8);
        hipLaunchKernelGGL(cvt_bf16, dim3(n8 / 256), dim3(256), 0, stream, K, Kbf, n8, 1.0f);
        hipLaunchKernelGGL(transposeV, dim3(1024), dim3(256), 0, stream, V, Vtbf);
        hipLaunchKernelGGL(l_pass, dim3(2048), dim3(256), 0, stream, Q, Kbf, wsR);
        hipLaunchKernelGGL(b_pass, dim3(1024), dim3(256), 0, stream, Q, Kbf, Vtbf, wsR, O, P);
    } else {
        hipLaunchKernelGGL(attn_fused, dim3(512), dim3(256), 0, stream, Q, K, V, O, P);
    }
}

// Round 9
// 250.866 us; speedup vs baseline: 1.0216x; 1.0216x over previous
//
#include <hip/hip_runtime.h>

#define SS 2048
#define DD 64
#define QB 64       // q rows per block (2 q-tiles x 32)
#define KVB 64      // kv rows per staged tile
#define NT (SS / KVB)

typedef unsigned short ushort_t;
typedef __attribute__((ext_vector_type(4)))  float f32x4;
typedef __attribute__((ext_vector_type(16))) float f32x16;
typedef __attribute__((ext_vector_type(8)))  short bf16x8;
typedef __attribute__((ext_vector_type(2)))  unsigned int u32x2;

static __device__ __forceinline__ unsigned short f2bf(float f) {
    unsigned u = __builtin_bit_cast(unsigned, f);
    u += 0x7FFFu + ((u >> 16) & 1u);
    return (unsigned short)(u >> 16);
}

static __device__ __forceinline__ f32x16 zero16() {
    f32x16 z;
#pragma unroll
    for (int i = 0; i < 16; ++i) z[i] = 0.f;
    return z;
}

union PFrag { bf16x8 v; unsigned w[4]; };

#define GLL16(src, dst) \
    __builtin_amdgcn_global_load_lds((const __attribute__((address_space(1))) void*)(src), \
                                     (__attribute__((address_space(3))) void*)(dst), 16, 0, 0)

// ---------------- prologue: fp32 -> bf16 ----------------
__global__ void cvt_bf16(const float* __restrict__ src, ushort_t* __restrict__ dst,
                         int n8, float scale)
{
    int i = blockIdx.x * blockDim.x + threadIdx.x;
    if (i >= n8) return;
    f32x4 a = ((const f32x4*)src)[2 * i];
    f32x4 b = ((const f32x4*)src)[2 * i + 1];
    bf16x8 o;
#pragma unroll
    for (int j = 0; j < 4; ++j) o[j] = (short)f2bf(a[j] * scale);
#pragma unroll
    for (int j = 0; j < 4; ++j) o[4 + j] = (short)f2bf(b[j] * scale);
    ((bf16x8*)dst)[i] = o;
}

// ---------------- prologue: V [h][kv][d] fp32 -> V^T [h][d][kv] bf16 ----------------
__global__ void transposeV(const float* __restrict__ V, ushort_t* __restrict__ Vt)
{
    __shared__ float tile[64][65];
    const int tid = threadIdx.x;
    const int hh = blockIdx.x >> 5;
    const int kt = blockIdx.x & 31;

#pragma unroll
    for (int it = 0; it < 4; ++it) {
        int m = it * 256 + tid;
        int r = m >> 4, c4 = m & 15;
        f32x4 v = *(const f32x4*)(V + ((size_t)(hh * SS + kt * 64 + r)) * DD + c4 * 4);
#pragma unroll
        for (int j = 0; j < 4; ++j) tile[r][c4 * 4 + j] = v[j];
    }
    __syncthreads();
#pragma unroll
    for (int it = 0; it < 2; ++it) {
        int m = it * 256 + tid;
        int d = m >> 3, c8 = m & 7;
        bf16x8 o;
#pragma unroll
        for (int j = 0; j < 8; ++j) o[j] = (short)f2bf(tile[c8 * 8 + j][d]);
        *(bf16x8*)(Vt + ((size_t)hh * DD + d) * SS + kt * 64 + c8 * 8) = o;
    }
}

// ---------------- main: R6-fused + coalesced P stores via per-wave LDS transpose ----------------
__global__ __launch_bounds__(256, 3)
void attn_main6(const float* __restrict__ gQ, const ushort_t* __restrict__ Kbf,
                const ushort_t* __restrict__ Vtbf, float* __restrict__ gO,
                float* __restrict__ gP)
{
    __shared__ float lsm[4][32];                               // per-wave partial denoms
    __shared__ __attribute__((aligned(16))) char shraw[33792]; // union: stage / osm
    __shared__ float pt[4][32][33];                            // per-wave P transpose tile
    ushort_t* stage = (ushort_t*)shraw;   // [2 buf][ K:4096 | V:4096 ] elems
    float*    osm   = (float*)shraw;      // [4][64][33] after main loop

    const int tid  = threadIdx.x;
    const int lane = tid & 63;
    const int wave = tid >> 6;
    const int lo5  = lane & 31;
    const int hi   = lane >> 5;
    const int qs   = wave >> 1;          // q sub-tile (0,1)
    const int sub  = wave & 1;           // kv sub within 64-tile (0,1)

    const int bid  = blockIdx.x;
    const int wg   = (bid & 7) * 128 + (bid >> 3);  // XCD-contiguous (4 heads/XCD)
    const int head = wg >> 5;
    const int q0b  = (wg & 31) * QB;

    const float*    Qh = gQ   + (size_t)head * SS * DD;
    const ushort_t* Kh = Kbf  + (size_t)head * SS * DD;
    const ushort_t* Vh = Vtbf + (size_t)head * DD * SS;   // [d][kv]
    float* Oh = gO + (size_t)head * SS * DD;
    float* Ph = gP + (size_t)head * SS * SS;

    const float SCALE = 0.125f * 1.44269504088896340736f; // (1/sqrt(64)) * log2(e)

    // ---- Q B-fragments from fp32 global (scale+log2e folded) ----
    const int qrow = q0b + qs * 32 + lo5;
    bf16x8 qf[4];
#pragma unroll
    for (int ks = 0; ks < 4; ++ks) {
        const float* qp = Qh + (size_t)qrow * DD + ks * 16 + hi * 8;
        f32x4 a = *(const f32x4*)(qp);
        f32x4 b = *(const f32x4*)(qp + 4);
        bf16x8 o;
#pragma unroll
        for (int j = 0; j < 4; ++j) o[j] = (short)f2bf(a[j] * SCALE);
#pragma unroll
        for (int j = 0; j < 4; ++j) o[4 + j] = (short)f2bf(b[j] * SCALE);
        qf[ks] = o;
    }

    // ---- staging addresses (source pre-swizzled, LDS dest linear) ----
    const int lgrp = lane >> 3;              // 0..7
    const int lchk = (lane & 7) ^ lgrp;      // involution chunk swizzle
    const ushort_t* srcK[2]; const ushort_t* srcV[2];
#pragma unroll
    for (int j = 0; j < 2; ++j) {
        int W = wave * 2 + j;                // 0..7 row-group
        srcK[j] = Kh + (size_t)(W * 8 + lgrp) * DD + lchk * 8;
        srcV[j] = Vh + (size_t)(W * 8 + lgrp) * SS + lchk * 8;
    }
    const int kvl = sub * 32 + lo5;          // this wave's K row in tile

    // ================= PASS A: denominator (max-free) =================
#pragma unroll
    for (int j = 0; j < 2; ++j) GLL16(srcK[j], stage + (wave * 2 + j) * 512);
    __syncthreads();

    float ls0 = 0.f, ls1 = 0.f;
    for (int t = 0; t < NT; ++t) {
        const int buf = t & 1;
        if (t + 1 < NT) {
#pragma unroll
            for (int j = 0; j < 2; ++j)
                GLL16(srcK[j] + (size_t)(t + 1) * KVB * DD,
                      stage + (buf ^ 1) * 8192 + (wave * 2 + j) * 512);
        }
        const ushort_t* Ksb = stage + buf * 8192;
        f32x16 acc = zero16();
#pragma unroll
        for (int ks = 0; ks < 4; ++ks) {
            bf16x8 kf = *(const bf16x8*)(Ksb + kvl * 64 + ((((ks * 2) + hi) ^ (kvl & 7)) << 3));
            acc = __builtin_amdgcn_mfma_f32_32x32x16_bf16(kf, qf[ks], acc, 0, 0, 0);
        }
#pragma unroll
        for (int r = 0; r < 16; r += 2) {
            ls0 += __builtin_exp2f(acc[r]);
            ls1 += __builtin_exp2f(acc[r + 1]);
        }
        __syncthreads();
    }
    float lsum = ls0 + ls1;
    lsum += __shfl_xor(lsum, 32);
    lsm[wave][lo5] = lsum;
    __syncthreads();
    const float rinv = 1.0f / (lsm[qs * 2][lo5] + lsm[qs * 2 + 1][lo5]);

    // ================= PASS B: scores, transposed P write, PV =================
    f32x16 o0 = zero16(), o1 = zero16();
    // coalesced-store lane mapping: lane = (rr row, cc col-chunk)
    const int rr = lane >> 3;                // 0..7
    const int cc = lane & 7;                 // 0..7 (x4 floats)
    float* prow0 = Ph + (size_t)(q0b + qs * 32) * SS + sub * 32;

#pragma unroll
    for (int j = 0; j < 2; ++j) {
        GLL16(srcK[j], stage + (wave * 2 + j) * 512);
        GLL16(srcV[j], stage + 4096 + (wave * 2 + j) * 512);
    }
    __syncthreads();

    for (int t = 0; t < NT; ++t) {
        const int buf = t & 1;
        if (t + 1 < NT) {
#pragma unroll
            for (int j = 0; j < 2; ++j) {
                GLL16(srcK[j] + (size_t)(t + 1) * KVB * DD,
                      stage + (buf ^ 1) * 8192 + (wave * 2 + j) * 512);
                GLL16(srcV[j] + (size_t)(t + 1) * KVB,
                      stage + (buf ^ 1) * 8192 + 4096 + (wave * 2 + j) * 512);
            }
        }
        const ushort_t* Ksb = stage + buf * 8192;
        const ushort_t* Vtb = Ksb + 4096;

        f32x16 acc = zero16();
#pragma unroll
        for (int ks = 0; ks < 4; ++ks) {
            bf16x8 kf = *(const bf16x8*)(Ksb + kvl * 64 + ((((ks * 2) + hi) ^ (kvl & 7)) << 3));
            acc = __builtin_amdgcn_mfma_f32_32x32x16_bf16(kf, qf[ks], acc, 0, 0, 0);
        }
        float pr[16];
#pragma unroll
        for (int r = 0; r < 16; ++r) pr[r] = __builtin_exp2f(acc[r]);

        // (1) write normalized P into per-wave LDS transpose tile (row lo5, col 8g+4hi)
#pragma unroll
        for (int g = 0; g < 4; ++g) {
            f32x4 st = { pr[4*g+0] * rinv, pr[4*g+1] * rinv, pr[4*g+2] * rinv, pr[4*g+3] * rinv };
            *(f32x4*)&pt[wave][lo5][g * 8 + hi * 4] = st;
        }

        // (2) pack unnormalized p to bf16 pairs (hides LDS write latency)
        unsigned u[8];
#pragma unroll
        for (int j = 0; j < 8; ++j)
            u[j] = (unsigned)f2bf(pr[2*j]) | ((unsigned)f2bf(pr[2*j+1]) << 16);

        unsigned s0 = __shfl_xor(u[0], 32), s1 = __shfl_xor(u[1], 32);
        unsigned s2 = __shfl_xor(u[2], 32), s3 = __shfl_xor(u[3], 32);
        unsigned s4 = __shfl_xor(u[4], 32), s5 = __shfl_xor(u[5], 32);
        unsigned s6 = __shfl_xor(u[6], 32), s7 = __shfl_xor(u[7], 32);
        PFrag pf0, pf1;
        pf0.w[0] = hi ? s2 : u[0];  pf0.w[1] = hi ? s3 : u[1];
        pf0.w[2] = hi ? u[2] : s0;  pf0.w[3] = hi ? u[3] : s1;
        pf1.w[0] = hi ? s6 : u[4];  pf1.w[1] = hi ? s7 : u[5];
        pf1.w[2] = hi ? u[6] : s4;  pf1.w[3] = hi ? u[7] : s5;

        // (3) PV: O^T[64d][32q] += V^T * P^T
#pragma unroll
        for (int dt = 0; dt < 2; ++dt) {
            int drow = dt * 32 + lo5;
            int c0 = ((sub * 4) + 0 + hi) ^ (drow & 7);
            int c1 = ((sub * 4) + 2 + hi) ^ (drow & 7);
            bf16x8 vf0 = *(const bf16x8*)(Vtb + drow * 64 + (c0 << 3));
            bf16x8 vf1 = *(const bf16x8*)(Vtb + drow * 64 + (c1 << 3));
            f32x16& od = dt ? o1 : o0;
            od = __builtin_amdgcn_mfma_f32_32x32x16_bf16(vf0, pf0.v, od, 0, 0, 0);
            od = __builtin_amdgcn_mfma_f32_32x32x16_bf16(vf1, pf1.v, od, 0, 0, 0);
        }

        // (4) read back transposed, store P coalesced (8 full 128B lines / instr)
        {
            float* pdst = prow0 + (size_t)t * KVB;
#pragma unroll
            for (int r4 = 0; r4 < 4; ++r4) {
                f32x4 v = *(const f32x4*)&pt[wave][r4 * 8 + rr][cc * 4];
                *(f32x4*)(pdst + (size_t)(r4 * 8 + rr) * SS + cc * 4) = v;
            }
        }

        __syncthreads();
    }

    // ================= epilogue: 2-way O reduce through reused LDS =================
#pragma unroll
    for (int dt = 0; dt < 2; ++dt) {
        const f32x16& od = dt ? o1 : o0;
#pragma unroll
        for (int g = 0; g < 4; ++g) {
#pragma unroll
            for (int j = 0; j < 4; ++j) {
                int d = dt * 32 + g * 8 + hi * 4 + j;
                osm[(wave * 64 + d) * 33 + lo5] = od[4 * g + j];
            }
        }
    }
    __syncthreads();
    {
        const int p  = tid >> 7;            // q sub-tile
        const int q  = (tid >> 2) & 31;
        const int d0 = (tid & 3) * 16;
        const float rq = 1.0f / (lsm[2 * p][q] + lsm[2 * p + 1][q]);
        float* op = Oh + (size_t)(q0b + p * 32 + q) * DD + d0;
#pragma unroll
        for (int v4 = 0; v4 < 4; ++v4) {
            f32x4 st;
#pragma unroll
            for (int j = 0; j < 4; ++j) {
                int d = d0 + v4 * 4 + j;
                st[j] = (osm[((2 * p) * 64 + d) * 33 + q] +
                         osm[((2 * p + 1) * 64 + d) * 33 + q]) * rq;
            }
            *(f32x4*)(op + v4 * 4) = st;
        }
    }
}

// ================= fallback (no-ws path) =================
__global__ __launch_bounds__(256, 2)
void attn_fused(const float* __restrict__ gQ, const float* __restrict__ gK,
                const float* __restrict__ gV, float* __restrict__ gO,
                float* __restrict__ gP)
{
    __shared__ unsigned short Qs[128 * DD];
    __shared__ unsigned short Ks[64 * DD];
    __shared__ unsigned short Vt[DD * 64];

    const int tid  = threadIdx.x;
    const int lane = tid & 63;
    const int wave = tid >> 6;
    const int lo5  = lane & 31;
    const int hi   = lane >> 5;

    const int head = blockIdx.x >> 4;
    const int q0b  = (blockIdx.x & 15) * 128;

    const float* Qh = gQ + (size_t)head * SS * DD;
    const float* Kh = gK + (size_t)head * SS * DD;
    const float* Vh = gV + (size_t)head * SS * DD;
    float* Oh = gO + (size_t)head * SS * DD;
    float* Ph = gP + (size_t)head * SS * SS;

    const float SCALE = 0.125f * 1.44269504088896340736f;

#pragma unroll
    for (int it = 0; it < 8; ++it) {
        int m = it * 256 + tid;
        int q = m >> 4, d4 = m & 15;
        f32x4 v = *(const f32x4*)(Qh + (size_t)(q0b + q) * DD + d4 * 4);
        unsigned a = (unsigned)f2bf(v.x * SCALE) | ((unsigned)f2bf(v.y * SCALE) << 16);
        unsigned b = (unsigned)f2bf(v.z * SCALE) | ((unsigned)f2bf(v.w * SCALE) << 16);
        u32x2 w; w.x = a; w.y = b;
        *(u32x2*)(Qs + q * 64 + d4 * 4) = w;
    }
    __syncthreads();

    const int qrow = wave * 32 + lo5;
    bf16x8 qf[4];
#pragma unroll
    for (int ks = 0; ks < 4; ++ks)
        qf[ks] = *(const bf16x8*)(Qs + qrow * 64 + ks * 16 + hi * 8);

    auto stageK = [&](int kv0) {
#pragma unroll
        for (int it = 0; it < 4; ++it) {
            int m = it * 256 + tid;
            int kv = m >> 4, d4 = m & 15;
            f32x4 v = *(const f32x4*)(Kh + (size_t)(kv0 + kv) * DD + d4 * 4);
            unsigned a = (unsigned)f2bf(v.x) | ((unsigned)f2bf(v.y) << 16);
            unsigned b = (unsigned)f2bf(v.z) | ((unsigned)f2bf(v.w) << 16);
            int c16 = (d4 >> 1) ^ (kv & 7);
            u32x2 w; w.x = a; w.y = b;
            *(u32x2*)(Ks + kv * 64 + c16 * 8 + (d4 & 1) * 4) = w;
        }
    };
    auto stageV = [&](int kv0) {
#pragma unroll
        for (int it = 0; it < 2; ++it) {
            int m = it * 256 + tid;
            int kv2 = m >> 4, d4 = m & 15;
            const float* p0 = Vh + (size_t)(kv0 + kv2 * 2) * DD + d4 * 4;
            f32x4 v0 = *(const f32x4*)(p0);
            f32x4 v1 = *(const f32x4*)(p0 + DD);
#pragma unroll
            for (int c = 0; c < 4; ++c) {
                int d = d4 * 4 + c;
                unsigned u = (unsigned)f2bf(v0[c]) | ((unsigned)f2bf(v1[c]) << 16);
                int c16 = (kv2 >> 2) ^ (d & 7);
                *(unsigned*)(Vt + d * 64 + c16 * 8 + (kv2 & 3) * 2) = u;
            }
        }
    };

    float m_run = -1e30f, l_run = 0.f;
    for (int kv0 = 0; kv0 < SS; kv0 += 64) {
        __syncthreads();
        stageK(kv0);
        __syncthreads();
#pragma unroll
        for (int sub = 0; sub < 2; ++sub) {
            f32x16 acc = zero16();
            int kvl = sub * 32 + lo5;
#pragma unroll
            for (int ks = 0; ks < 4; ++ks) {
                bf16x8 kf = *(const bf16x8*)(Ks + kvl * 64 + ((((ks * 2) + hi) ^ (kvl & 7)) << 3));
                acc = __builtin_amdgcn_mfma_f32_32x32x16_bf16(kf, qf[ks], acc, 0, 0, 0);
            }
            float tm = acc[0];
#pragma unroll
            for (int r = 1; r < 16; ++r) tm = fmaxf(tm, acc[r]);
            float mn = fmaxf(m_run, tm);
            float sum = 0.f;
#pragma unroll
            for (int r = 0; r < 16; ++r) sum += __builtin_exp2f(acc[r] - mn);
            l_run = l_run * __builtin_exp2f(m_run - mn) + sum;
            m_run = mn;
        }
    }
    {
        float mo = __shfl_xor(m_run, 32);
        float mf = fmaxf(m_run, mo);
        float la = l_run * __builtin_exp2f(m_run - mf);
        float lb = __shfl_xor(la, 32);
        l_run = la + lb;
        m_run = mf;
    }
    const float rinv = 1.0f / l_run;

    f32x16 o0 = zero16(), o1 = zero16();
    const int qg = q0b + wave * 32 + lo5;
    float* prow_base = Ph + (size_t)qg * SS;

    for (int kv0 = 0; kv0 < SS; kv0 += 64) {
        __syncthreads();
        stageK(kv0);
        stageV(kv0);
        __syncthreads();
#pragma unroll
        for (int sub = 0; sub < 2; ++sub) {
            f32x16 acc = zero16();
            int kvl = sub * 32 + lo5;
#pragma unroll
            for (int ks = 0; ks < 4; ++ks) {
                bf16x8 kf = *(const bf16x8*)(Ks + kvl * 64 + ((((ks * 2) + hi) ^ (kvl & 7)) << 3));
                acc = __builtin_amdgcn_mfma_f32_32x32x16_bf16(kf, qf[ks], acc, 0, 0, 0);
            }
            float pr[16];
#pragma unroll
            for (int r = 0; r < 16; ++r) pr[r] = __builtin_exp2f(acc[r] - m_run);

            float* prow = prow_base + kv0 + sub * 32;
#pragma unroll
            for (int g = 0; g < 4; ++g) {
                f32x4 st = { pr[4*g+0] * rinv, pr[4*g+1] * rinv, pr[4*g+2] * rinv, pr[4*g+3] * rinv };
                *(f32x4*)(prow + g * 8 + hi * 4) = st;
            }

            unsigned u[8];
#pragma unroll
            for (int j = 0; j < 8; ++j)
                u[j] = (unsigned)f2bf(pr[2*j]) | ((unsigned)f2bf(pr[2*j+1]) << 16);

            unsigned s0 = __shfl_xor(u[0], 32), s1 = __shfl_xor(u[1], 32);
            unsigned s2 = __shfl_xor(u[2], 32), s3 = __shfl_xor(u[3], 32);
            unsigned s4 = __shfl_xor(u[4], 32), s5 = __shfl_xor(u[5], 32);
            unsigned s6 = __shfl_xor(u[6], 32), s7 = __shfl_xor(u[7], 32);
            PFrag pf0, pf1;
            pf0.w[0] = hi ? s2 : u[0];  pf0.w[1] = hi ? s3 : u[1];
            pf0.w[2] = hi ? u[2] : s0;  pf0.w[3] = hi ? u[3] : s1;
            pf1.w[0] = hi ? s6 : u[4];  pf1.w[1] = hi ? s7 : u[5];
            pf1.w[2] = hi ? u[6] : s4;  pf1.w[3] = hi ? u[7] : s5;

#pragma unroll
            for (int dt = 0; dt < 2; ++dt) {
                int drow = dt * 32 + lo5;
                int c0 = ((sub * 4) + 0 + hi) ^ (drow & 7);
                int c1 = ((sub * 4) + 2 + hi) ^ (drow & 7);
                bf16x8 vf0 = *(const bf16x8*)(Vt + drow * 64 + (c0 << 3));
                bf16x8 vf1 = *(const bf16x8*)(Vt + drow * 64 + (c1 << 3));
                f32x16& od = dt ? o1 : o0;
                od = __builtin_amdgcn_mfma_f32_32x32x16_bf16(vf0, pf0.v, od, 0, 0, 0);
                od = __builtin_amdgcn_mfma_f32_32x32x16_bf16(vf1, pf1.v, od, 0, 0, 0);
            }
        }
    }

    float* orow = Oh + (size_t)qg * DD;
#pragma unroll
    for (int dt = 0; dt < 2; ++dt) {
        const f32x16& od = dt ? o1 : o0;
#pragma unroll
        for (int g = 0; g < 4; ++g) {
            f32x4 st = { od[4*g+0] * rinv, od[4*g+1] * rinv, od[4*g+2] * rinv, od[4*g+3] * rinv };
            *(f32x4*)(orow + dt * 32 + g * 8 + hi * 4) = st;
        }
    }
}

extern "C" void kernel_launch(void* const* d_in, const int* in_sizes, int n_in,
                              void* d_out, int out_size, void* d_ws, size_t ws_size,
                              hipStream_t stream) {
    const float* Q = (const float*)d_in[0];
    const float* K = (const float*)d_in[1];
    const float* V = (const float*)d_in[2];
    float* O = (float*)d_out;
    float* P = O + (size_t)2 * 16 * SS * DD;

    const size_t HD = (size_t)32 * SS * DD;           // elems per tensor
    const size_t need = 2 * HD * sizeof(ushort_t);    // K bf16 + V^T bf16 ≈ 16.8 MB

    if (ws_size >= need) {
        ushort_t* Kbf  = (ushort_t*)d_ws;
        ushort_t* Vtbf = Kbf + HD;
        int n8 = (int)(HD / 8);
        hipLaunchKernelGGL(cvt_bf16, dim3(n8 / 256), dim3(256), 0, stream, K, Kbf, n8, 1.0f);
        hipLaunchKernelGGL(transposeV, dim3(1024), dim3(256), 0, stream, V, Vtbf);
        hipLaunchKernelGGL(attn_main6, dim3(1024), dim3(256), 0, stream, Q, Kbf, Vtbf, O, P);
    } else {
        hipLaunchKernelGGL(attn_fused, dim3(512), dim3(256), 0, stream, Q, K, V, O, P);
    }
}

// Round 10
// 250.201 us; speedup vs baseline: 1.0243x; 1.0027x over previous
//
#include <hip/hip_runtime.h>

#define SS 2048
#define DD 64
#define QB 64       // q rows per block (2 q-halves x 32)
#define KVB 64      // kv rows per tile
#define NT (SS / KVB)

typedef unsigned short ushort_t;
typedef __attribute__((ext_vector_type(4)))  float f32x4;
typedef __attribute__((ext_vector_type(16))) float f32x16;
typedef __attribute__((ext_vector_type(8)))  short bf16x8;
typedef __attribute__((ext_vector_type(2)))  unsigned int u32x2;

static __device__ __forceinline__ unsigned short f2bf(float f) {
    unsigned u = __builtin_bit_cast(unsigned, f);
    u += 0x7FFFu + ((u >> 16) & 1u);
    return (unsigned short)(u >> 16);
}

static __device__ __forceinline__ f32x16 zero16() {
    f32x16 z;
#pragma unroll
    for (int i = 0; i < 16; ++i) z[i] = 0.f;
    return z;
}

union PFrag { bf16x8 v; unsigned w[4]; };

#define GLL16(src, dst) \
    __builtin_amdgcn_global_load_lds((const __attribute__((address_space(1))) void*)(src), \
                                     (__attribute__((address_space(3))) void*)(dst), 16, 0, 0)

// ---------------- prologue: fp32 -> bf16 ----------------
__global__ void cvt_bf16(const float* __restrict__ src, ushort_t* __restrict__ dst,
                         int n8, float scale)
{
    int i = blockIdx.x * blockDim.x + threadIdx.x;
    if (i >= n8) return;
    f32x4 a = ((const f32x4*)src)[2 * i];
    f32x4 b = ((const f32x4*)src)[2 * i + 1];
    bf16x8 o;
#pragma unroll
    for (int j = 0; j < 4; ++j) o[j] = (short)f2bf(a[j] * scale);
#pragma unroll
    for (int j = 0; j < 4; ++j) o[4 + j] = (short)f2bf(b[j] * scale);
    ((bf16x8*)dst)[i] = o;
}

// ---------------- prologue: V [h][kv][d] fp32 -> V^T [h][d][kv] bf16 ----------------
__global__ void transposeV(const float* __restrict__ V, ushort_t* __restrict__ Vt)
{
    __shared__ float tile[64][65];
    const int tid = threadIdx.x;
    const int hh = blockIdx.x >> 5;
    const int kt = blockIdx.x & 31;

#pragma unroll
    for (int it = 0; it < 4; ++it) {
        int m = it * 256 + tid;
        int r = m >> 4, c4 = m & 15;
        f32x4 v = *(const f32x4*)(V + ((size_t)(hh * SS + kt * 64 + r)) * DD + c4 * 4);
#pragma unroll
        for (int j = 0; j < 4; ++j) tile[r][c4 * 4 + j] = v[j];
    }
    __syncthreads();
#pragma unroll
    for (int it = 0; it < 2; ++it) {
        int m = it * 256 + tid;
        int d = m >> 3, c8 = m & 7;
        bf16x8 o;
#pragma unroll
        for (int j = 0; j < 8; ++j) o[j] = (short)f2bf(tile[c8 * 8 + j][d]);
        *(bf16x8*)(Vt + ((size_t)hh * DD + d) * SS + kt * 64 + c8 * 8) = o;
    }
}

// ---------------- main: barrier-free wave-private pipeline ----------------
__global__ __launch_bounds__(256, 2)
void attn_main7(const float* __restrict__ gQ, const ushort_t* __restrict__ Kbf,
                const ushort_t* __restrict__ Vtbf, float* __restrict__ gO,
                float* __restrict__ gP)
{
    __shared__ float lsm[4][2][32];                            // [wave][q-half][q]
    __shared__ __attribute__((aligned(16))) char shraw[65536]; // per-wave stage / osm union
    ushort_t* stage = (ushort_t*)shraw;   // wave w: [w*8192 .. ) 16KB: 2 buf x (K 4KB | V 4KB)
    float*    osm   = (float*)shraw;      // [4][64][33] after loop

    const int tid  = threadIdx.x;
    const int lane = tid & 63;
    const int wave = tid >> 6;
    const int lo5  = lane & 31;
    const int hi   = lane >> 5;
    const int qs   = wave >> 1;           // q-half (0,1)
    const int sub  = wave & 1;            // kv-half within 64-tile (0,1)

    const int bid  = blockIdx.x;
    const int wg   = (bid & 7) * 128 + (bid >> 3);   // XCD-contiguous
    const int head = wg >> 5;
    const int q0b  = (wg & 31) * QB;

    const float*    Qh = gQ   + (size_t)head * SS * DD;
    const ushort_t* Kh = Kbf  + (size_t)head * SS * DD;
    const ushort_t* Vh = Vtbf + (size_t)head * DD * SS;   // [d][kv]
    float* Oh = gO + (size_t)head * SS * DD;
    float* Ph = gP + (size_t)head * SS * SS;

    const float SCALE = 0.125f * 1.44269504088896340736f;

    // ---- Q fragments, both q-halves ----
    bf16x8 qf2[2][4];
#pragma unroll
    for (int p = 0; p < 2; ++p)
#pragma unroll
        for (int ks = 0; ks < 4; ++ks) {
            const float* qp = Qh + (size_t)(q0b + p * 32 + lo5) * DD + ks * 16 + hi * 8;
            f32x4 a = *(const f32x4*)(qp);
            f32x4 b = *(const f32x4*)(qp + 4);
            bf16x8 o;
#pragma unroll
            for (int j = 0; j < 4; ++j) o[j] = (short)f2bf(a[j] * SCALE);
#pragma unroll
            for (int j = 0; j < 4; ++j) o[4 + j] = (short)f2bf(b[j] * SCALE);
            qf2[p][ks] = o;
        }

    // ================= PASS A: denominators, direct-L2, kv quarter per wave =================
    float la00 = 0.f, la01 = 0.f, la10 = 0.f, la11 = 0.f;
#pragma unroll 2
    for (int t = 0; t < 8; ++t) {
        int kv0 = wave * 512 + t * 64;
#pragma unroll
        for (int s = 0; s < 2; ++s) {
            const ushort_t* kp = Kh + (size_t)(kv0 + s * 32 + lo5) * DD + hi * 8;
            bf16x8 kf[4];
#pragma unroll
            for (int ks = 0; ks < 4; ++ks) kf[ks] = *(const bf16x8*)(kp + ks * 16);
            f32x16 a0 = zero16(), a1 = zero16();
#pragma unroll
            for (int ks = 0; ks < 4; ++ks) {
                a0 = __builtin_amdgcn_mfma_f32_32x32x16_bf16(kf[ks], qf2[0][ks], a0, 0, 0, 0);
                a1 = __builtin_amdgcn_mfma_f32_32x32x16_bf16(kf[ks], qf2[1][ks], a1, 0, 0, 0);
            }
#pragma unroll
            for (int r = 0; r < 16; r += 2) {
                la00 += __builtin_exp2f(a0[r]);
                la01 += __builtin_exp2f(a0[r + 1]);
                la10 += __builtin_exp2f(a1[r]);
                la11 += __builtin_exp2f(a1[r + 1]);
            }
        }
    }
    {
        float l0 = la00 + la01, l1 = la10 + la11;
        l0 += __shfl_xor(l0, 32);
        l1 += __shfl_xor(l1, 32);
        lsm[wave][0][lo5] = l0;
        lsm[wave][1][lo5] = l1;
    }
    __syncthreads();
    const float rinv = 1.0f / (lsm[0][qs][lo5] + lsm[1][qs][lo5] +
                               lsm[2][qs][lo5] + lsm[3][qs][lo5]);

    // ================= PASS B: barrier-free, wave-private staging =================
    ushort_t* wbase = stage + wave * 8192;      // 16KB per wave (ushort units)

    // staging source addresses (pre-swizzled so LDS dest stays linear)
    const int l8g = lane >> 3, l8c = lane & 7;
    const int kchk = l8c ^ l8g;                 // K involution (8 chunks/row)
    const int l4g = lane >> 2, l4c = lane & 3;
    const int vchk = l4c ^ (l4g & 3);           // V involution (4 chunks/row)
    const ushort_t* sK[4];
    const ushort_t* sV[4];
#pragma unroll
    for (int j = 0; j < 4; ++j) {
        sK[j] = Kh + (size_t)(sub * 32 + j * 8 + l8g) * DD + kchk * 8;
        sV[j] = Vh + (size_t)(j * 16 + l4g) * SS + sub * 32 + vchk * 8;
    }

    auto STAGE_B = [&](int tt, int b) {
        ushort_t* kb = wbase + b * 4096;
#pragma unroll
        for (int j = 0; j < 4; ++j)
            GLL16(sK[j] + (size_t)tt * KVB * DD, kb + j * 512);
#pragma unroll
        for (int j = 0; j < 4; ++j)
            GLL16(sV[j] + tt * KVB, kb + 2048 + j * 512);
    };

    f32x16 o0 = zero16(), o1 = zero16();
    const int qrow = q0b + qs * 32 + lo5;
    float* prow_base = Ph + (size_t)qrow * SS;

    STAGE_B(0, 0);                               // 8 ops in flight

    for (int t = 0; t < NT; ++t) {
        const int b = t & 1;
        if (t + 1 < NT) STAGE_B(t + 1, b ^ 1);   // issue next-tile loads FIRST
        __builtin_amdgcn_sched_barrier(0);
        // wait: this tile's 8 GLLs counted-done. Newer-in-FIFO ops left in flight:
        //   t==0   : GLL(1)x8                      -> vmcnt(8)
        //   middle : GLL(t+1)x8 + stores(t-1)x4    -> vmcnt(12)
        //   last   : stores(t-1)x4                 -> vmcnt(4)
        if (t == 0)            asm volatile("s_waitcnt vmcnt(8)"  ::: "memory");
        else if (t + 1 < NT)   asm volatile("s_waitcnt vmcnt(12)" ::: "memory");
        else                   asm volatile("s_waitcnt vmcnt(4)"  ::: "memory");
        __builtin_amdgcn_sched_barrier(0);

        const ushort_t* Ksb = wbase + b * 4096;          // K half: [32 rows][128B]
        const ushort_t* Vtb = Ksb + 2048;                // V half: [64 rows][64B]

        f32x16 acc = zero16();
#pragma unroll
        for (int ks = 0; ks < 4; ++ks) {
            bf16x8 kf = *(const bf16x8*)(Ksb + lo5 * 64 + ((((ks * 2) + hi) ^ (lo5 & 7)) << 3));
            acc = __builtin_amdgcn_mfma_f32_32x32x16_bf16(kf, qf2[qs][ks], acc, 0, 0, 0);
        }
        float pr[16];
#pragma unroll
        for (int r = 0; r < 16; ++r) pr[r] = __builtin_exp2f(acc[r]);

        // normalized P store (ages out across >=2 iterations, never drained in-loop)
        float* prow = prow_base + t * KVB + sub * 32;
#pragma unroll
        for (int g = 0; g < 4; ++g) {
            f32x4 st = { pr[4*g+0] * rinv, pr[4*g+1] * rinv, pr[4*g+2] * rinv, pr[4*g+3] * rinv };
            *(f32x4*)(prow + g * 8 + hi * 4) = st;
        }
        __builtin_amdgcn_sched_barrier(0);       // pin stores before next iter's GLLs

        // pack + half-wave exchange -> P^T B-frags
        unsigned u[8];
#pragma unroll
        for (int j = 0; j < 8; ++j)
            u[j] = (unsigned)f2bf(pr[2*j]) | ((unsigned)f2bf(pr[2*j+1]) << 16);
        unsigned s0 = __shfl_xor(u[0], 32), s1 = __shfl_xor(u[1], 32);
        unsigned s2 = __shfl_xor(u[2], 32), s3 = __shfl_xor(u[3], 32);
        unsigned s4 = __shfl_xor(u[4], 32), s5 = __shfl_xor(u[5], 32);
        unsigned s6 = __shfl_xor(u[6], 32), s7 = __shfl_xor(u[7], 32);
        PFrag pf0, pf1;
        pf0.w[0] = hi ? s2 : u[0];  pf0.w[1] = hi ? s3 : u[1];
        pf0.w[2] = hi ? u[2] : s0;  pf0.w[3] = hi ? u[3] : s1;
        pf1.w[0] = hi ? s6 : u[4];  pf1.w[1] = hi ? s7 : u[5];
        pf1.w[2] = hi ? u[6] : s4;  pf1.w[3] = hi ? u[7] : s5;

        // PV: O^T += V^T * P^T   (V half: row d, 4 chunks, XOR(d&3) swizzle)
#pragma unroll
        for (int dt = 0; dt < 2; ++dt) {
            int drow = dt * 32 + lo5;
            int c0 = (0 + hi) ^ (drow & 3);
            int c1 = (2 + hi) ^ (drow & 3);
            bf16x8 vf0 = *(const bf16x8*)(Vtb + drow * 32 + (c0 << 3));
            bf16x8 vf1 = *(const bf16x8*)(Vtb + drow * 32 + (c1 << 3));
            f32x16& od = dt ? o1 : o0;
            od = __builtin_amdgcn_mfma_f32_32x32x16_bf16(vf0, pf0.v, od, 0, 0, 0);
            od = __builtin_amdgcn_mfma_f32_32x32x16_bf16(vf1, pf1.v, od, 0, 0, 0);
        }
    }

    // ================= epilogue: 2-way O reduce through reused LDS =================
    __syncthreads();   // full drain; stage -> osm reuse
#pragma unroll
    for (int dt = 0; dt < 2; ++dt) {
        const f32x16& od = dt ? o1 : o0;
#pragma unroll
        for (int g = 0; g < 4; ++g) {
#pragma unroll
            for (int j = 0; j < 4; ++j) {
                int d = dt * 32 + g * 8 + hi * 4 + j;
                osm[(wave * 64 + d) * 33 + lo5] = od[4 * g + j];
            }
        }
    }
    __syncthreads();
    {
        const int p  = tid >> 7;
        const int q  = (tid >> 2) & 31;
        const int d0 = (tid & 3) * 16;
        const float rq = 1.0f / (lsm[0][p][q] + lsm[1][p][q] + lsm[2][p][q] + lsm[3][p][q]);
        float* op = Oh + (size_t)(q0b + p * 32 + q) * DD + d0;
#pragma unroll
        for (int v4 = 0; v4 < 4; ++v4) {
            f32x4 st;
#pragma unroll
            for (int j = 0; j < 4; ++j) {
                int d = d0 + v4 * 4 + j;
                st[j] = (osm[((2 * p) * 64 + d) * 33 + q] +
                         osm[((2 * p + 1) * 64 + d) * 33 + q]) * rq;
            }
            *(f32x4*)(op + v4 * 4) = st;
        }
    }
}

// ================= fallback (no-ws path) =================
__global__ __launch_bounds__(256, 2)
void attn_fused(const float* __restrict__ gQ, const float* __restrict__ gK,
                const float* __restrict__ gV, float* __restrict__ gO,
                float* __restrict__ gP)
{
    __shared__ unsigned short Qs[128 * DD];
    __shared__ unsigned short Ks[64 * DD];
    __shared__ unsigned short Vt[DD * 64];

    const int tid  = threadIdx.x;
    const int lane = tid & 63;
    const int wave = tid >> 6;
    const int lo5  = lane & 31;
    const int hi   = lane >> 5;

    const int head = blockIdx.x >> 4;
    const int q0b  = (blockIdx.x & 15) * 128;

    const float* Qh = gQ + (size_t)head * SS * DD;
    const float* Kh = gK + (size_t)head * SS * DD;
    const float* Vh = gV + (size_t)head * SS * DD;
    float* Oh = gO + (size_t)head * SS * DD;
    float* Ph = gP + (size_t)head * SS * SS;

    const float SCALE = 0.125f * 1.44269504088896340736f;

#pragma unroll
    for (int it = 0; it < 8; ++it) {
        int m = it * 256 + tid;
        int q = m >> 4, d4 = m & 15;
        f32x4 v = *(const f32x4*)(Qh + (size_t)(q0b + q) * DD + d4 * 4);
        unsigned a = (unsigned)f2bf(v.x * SCALE) | ((unsigned)f2bf(v.y * SCALE) << 16);
        unsigned b = (unsigned)f2bf(v.z * SCALE) | ((unsigned)f2bf(v.w * SCALE) << 16);
        u32x2 w; w.x = a; w.y = b;
        *(u32x2*)(Qs + q * 64 + d4 * 4) = w;
    }
    __syncthreads();

    const int qrow = wave * 32 + lo5;
    bf16x8 qf[4];
#pragma unroll
    for (int ks = 0; ks < 4; ++ks)
        qf[ks] = *(const bf16x8*)(Qs + qrow * 64 + ks * 16 + hi * 8);

    auto stageK = [&](int kv0) {
#pragma unroll
        for (int it = 0; it < 4; ++it) {
            int m = it * 256 + tid;
            int kv = m >> 4, d4 = m & 15;
            f32x4 v = *(const f32x4*)(Kh + (size_t)(kv0 + kv) * DD + d4 * 4);
            unsigned a = (unsigned)f2bf(v.x) | ((unsigned)f2bf(v.y) << 16);
            unsigned b = (unsigned)f2bf(v.z) | ((unsigned)f2bf(v.w) << 16);
            int c16 = (d4 >> 1) ^ (kv & 7);
            u32x2 w; w.x = a; w.y = b;
            *(u32x2*)(Ks + kv * 64 + c16 * 8 + (d4 & 1) * 4) = w;
        }
    };
    auto stageV = [&](int kv0) {
#pragma unroll
        for (int it = 0; it < 2; ++it) {
            int m = it * 256 + tid;
            int kv2 = m >> 4, d4 = m & 15;
            const float* p0 = Vh + (size_t)(kv0 + kv2 * 2) * DD + d4 * 4;
            f32x4 v0 = *(const f32x4*)(p0);
            f32x4 v1 = *(const f32x4*)(p0 + DD);
#pragma unroll
            for (int c = 0; c < 4; ++c) {
                int d = d4 * 4 + c;
                unsigned u = (unsigned)f2bf(v0[c]) | ((unsigned)f2bf(v1[c]) << 16);
                int c16 = (kv2 >> 2) ^ (d & 7);
                *(unsigned*)(Vt + d * 64 + c16 * 8 + (kv2 & 3) * 2) = u;
            }
        }
    };

    float m_run = -1e30f, l_run = 0.f;
    for (int kv0 = 0; kv0 < SS; kv0 += 64) {
        __syncthreads();
        stageK(kv0);
        __syncthreads();
#pragma unroll
        for (int sub = 0; sub < 2; ++sub) {
            f32x16 acc = zero16();
            int kvl = sub * 32 + lo5;
#pragma unroll
            for (int ks = 0; ks < 4; ++ks) {
                bf16x8 kf = *(const bf16x8*)(Ks + kvl * 64 + ((((ks * 2) + hi) ^ (kvl & 7)) << 3));
                acc = __builtin_amdgcn_mfma_f32_32x32x16_bf16(kf, qf[ks], acc, 0, 0, 0);
            }
            float tm = acc[0];
#pragma unroll
            for (int r = 1; r < 16; ++r) tm = fmaxf(tm, acc[r]);
            float mn = fmaxf(m_run, tm);
            float sum = 0.f;
#pragma unroll
            for (int r = 0; r < 16; ++r) sum += __builtin_exp2f(acc[r] - mn);
            l_run = l_run * __builtin_exp2f(m_run - mn) + sum;
            m_run = mn;
        }
    }
    {
        float mo = __shfl_xor(m_run, 32);
        float mf = fmaxf(m_run, mo);
        float la = l_run * __builtin_exp2f(m_run - mf);
        float lb = __shfl_xor(la, 32);
        l_run = la + lb;
        m_run = mf;
    }
    const float rinv = 1.0f / l_run;

    f32x16 o0 = zero16(), o1 = zero16();
    const int qg = q0b + wave * 32 + lo5;
    float* prow_base = Ph + (size_t)qg * SS;

    for (int kv0 = 0; kv0 < SS; kv0 += 64) {
        __syncthreads();
        stageK(kv0);
        stageV(kv0);
        __syncthreads();
#pragma unroll
        for (int sub = 0; sub < 2; ++sub) {
            f32x16 acc = zero16();
            int kvl = sub * 32 + lo5;
#pragma unroll
            for (int ks = 0; ks < 4; ++ks) {
                bf16x8 kf = *(const bf16x8*)(Ks + kvl * 64 + ((((ks * 2) + hi) ^ (kvl & 7)) << 3));
                acc = __builtin_amdgcn_mfma_f32_32x32x16_bf16(kf, qf[ks], acc, 0, 0, 0);
            }
            float pr[16];
#pragma unroll
            for (int r = 0; r < 16; ++r) pr[r] = __builtin_exp2f(acc[r] - m_run);

            float* prow = prow_base + kv0 + sub * 32;
#pragma unroll
            for (int g = 0; g < 4; ++g) {
                f32x4 st = { pr[4*g+0] * rinv, pr[4*g+1] * rinv, pr[4*g+2] * rinv, pr[4*g+3] * rinv };
                *(f32x4*)(prow + g * 8 + hi * 4) = st;
            }

            unsigned u[8];
#pragma unroll
            for (int j = 0; j < 8; ++j)
                u[j] = (unsigned)f2bf(pr[2*j]) | ((unsigned)f2bf(pr[2*j+1]) << 16);

            unsigned s0 = __shfl_xor(u[0], 32), s1 = __shfl_xor(u[1], 32);
            unsigned s2 = __shfl_xor(u[2], 32), s3 = __shfl_xor(u[3], 32);
            unsigned s4 = __shfl_xor(u[4], 32), s5 = __shfl_xor(u[5], 32);
            unsigned s6 = __shfl_xor(u[6], 32), s7 = __shfl_xor(u[7], 32);
            PFrag pf0, pf1;
            pf0.w[0] = hi ? s2 : u[0];  pf0.w[1] = hi ? s3 : u[1];
            pf0.w[2] = hi ? u[2] : s0;  pf0.w[3] = hi ? u[3] : s1;
            pf1.w[0] = hi ? s6 : u[4];  pf1.w[1] = hi ? s7 : u[5];
            pf1.w[2] = hi ? u[6] : s4;  pf1.w[3] = hi ? u[7] : s5;

#pragma unroll
            for (int dt = 0; dt < 2; ++dt) {
                int drow = dt * 32 + lo5;
                int c0 = ((sub * 4) + 0 + hi) ^ (drow & 7);
                int c1 = ((sub * 4) + 2 + hi) ^ (drow & 7);
                bf16x8 vf0 = *(const bf16x8*)(Vt + drow * 64 + (c0 << 3));
                bf16x8 vf1 = *(const bf16x8*)(Vt + drow * 64 + (c1 << 3));
                f32x16& od = dt ? o1 : o0;
                od = __builtin_amdgcn_mfma_f32_32x32x16_bf16(vf0, pf0.v, od, 0, 0, 0);
                od = __builtin_amdgcn_mfma_f32_32x32x16_bf16(vf1, pf1.v, od, 0, 0, 0);
            }
        }
    }

    float* orow = Oh + (size_t)qg * DD;
#pragma unroll
    for (int dt = 0; dt < 2; ++dt) {
        const f32x16& od = dt ? o1 : o0;
#pragma unroll
        for (int g = 0; g < 4; ++g) {
            f32x4 st = { od[4*g+0] * rinv, od[4*g+1] * rinv, od[4*g+2] * rinv, od[4*g+3] * rinv };
            *(f32x4*)(orow + dt * 32 + g * 8 + hi * 4) = st;
        }
    }
}

extern "C" void kernel_launch(void* const* d_in, const int* in_sizes, int n_in,
                              void* d_out, int out_size, void* d_ws, size_t ws_size,
                              hipStream_t stream) {
    const float* Q = (const float*)d_in[0];
    const float* K = (const float*)d_in[1];
    const float* V = (const float*)d_in[2];
    float* O = (float*)d_out;
    float* P = O + (size_t)2 * 16 * SS * DD;

    const size_t HD = (size_t)32 * SS * DD;           // elems per tensor
    const size_t need = 2 * HD * sizeof(ushort_t);    // K bf16 + V^T bf16 ≈ 16.8 MB

    if (ws_size >= need) {
        ushort_t* Kbf  = (ushort_t*)d_ws;
        ushort_t* Vtbf = Kbf + HD;
        int n8 = (int)(HD / 8);
        hipLaunchKernelGGL(cvt_bf16, dim3(n8 / 256), dim3(256), 0, stream, K, Kbf, n8, 1.0f);
        hipLaunchKernelGGL(transposeV, dim3(1024), dim3(256), 0, stream, V, Vtbf);
        hipLaunchKernelGGL(attn_main7, dim3(1024), dim3(256), 0, stream, Q, Kbf, Vtbf, O, P);
    } else {
        hipLaunchKernelGGL(attn_fused, dim3(512), dim3(256), 0, stream, Q, K, V, O, P);
    }
}

// Round 12
// 216.936 us; speedup vs baseline: 1.1814x; 1.1533x over previous
//
#include <hip/hip_runtime.h>

#define SS 2048
#define DD 64
#define QB 64        // q rows per block (2 q-tiles x 32)
#define KVB 128      // kv rows per staged tile (doubled vs R6)
#define NT (SS / KVB)

typedef unsigned short ushort_t;
typedef __attribute__((ext_vector_type(4)))  float f32x4;
typedef __attribute__((ext_vector_type(16))) float f32x16;
typedef __attribute__((ext_vector_type(8)))  short bf16x8;
typedef __attribute__((ext_vector_type(2)))  unsigned int u32x2;

static __device__ __forceinline__ unsigned short f2bf(float f) {
    unsigned u = __builtin_bit_cast(unsigned, f);
    u += 0x7FFFu + ((u >> 16) & 1u);
    return (unsigned short)(u >> 16);
}

static __device__ __forceinline__ f32x16 zero16() {
    f32x16 z;
#pragma unroll
    for (int i = 0; i < 16; ++i) z[i] = 0.f;
    return z;
}

union PFrag { bf16x8 v; unsigned w[4]; };

#define GLL16(src, dst) \
    __builtin_amdgcn_global_load_lds((const __attribute__((address_space(1))) void*)(src), \
                                     (__attribute__((address_space(3))) void*)(dst), 16, 0, 0)

// ---------------- merged prologue: K fp32->bf16 (blocks 0..2047), V transpose (2048..3071) ----------------
__global__ void prep(const float* __restrict__ K, const float* __restrict__ V,
                     ushort_t* __restrict__ Kbf, ushort_t* __restrict__ Vt)
{
    const int tid = threadIdx.x;
    if (blockIdx.x < 2048) {
        int i = blockIdx.x * 256 + tid;          // n8 = 32*2048*64/8 = 524288
        f32x4 a = ((const f32x4*)K)[2 * i];
        f32x4 b = ((const f32x4*)K)[2 * i + 1];
        bf16x8 o;
#pragma unroll
        for (int j = 0; j < 4; ++j) o[j] = (short)f2bf(a[j]);
#pragma unroll
        for (int j = 0; j < 4; ++j) o[4 + j] = (short)f2bf(b[j]);
        ((bf16x8*)Kbf)[i] = o;
        return;
    }
    __shared__ float tile[64][65];
    const int bid2 = blockIdx.x - 2048;
    const int hh = bid2 >> 5;
    const int kt = bid2 & 31;
#pragma unroll
    for (int it = 0; it < 4; ++it) {
        int m = it * 256 + tid;
        int r = m >> 4, c4 = m & 15;
        f32x4 v = *(const f32x4*)(V + ((size_t)(hh * SS + kt * 64 + r)) * DD + c4 * 4);
#pragma unroll
        for (int j = 0; j < 4; ++j) tile[r][c4 * 4 + j] = v[j];
    }
    __syncthreads();
#pragma unroll
    for (int it = 0; it < 2; ++it) {
        int m = it * 256 + tid;
        int d = m >> 3, c8 = m & 7;
        bf16x8 o;
#pragma unroll
        for (int j = 0; j < 8; ++j) o[j] = (short)f2bf(tile[c8 * 8 + j][d]);
        *(bf16x8*)(Vt + ((size_t)hh * DD + d) * SS + kt * 64 + c8 * 8) = o;
    }
}

// ---------------- main: R6 structure with KVB=128 (half the barrier phases) ----------------
__global__ __launch_bounds__(256, 2)
void attn_main9(const float* __restrict__ gQ, const ushort_t* __restrict__ Kbf,
                const ushort_t* __restrict__ Vtbf, float* __restrict__ gO,
                float* __restrict__ gP)
{
    __shared__ float lsm[4][32];                               // per-wave partial denoms
    __shared__ __attribute__((aligned(16))) char shraw[65536]; // [2 buf][K 16KB | V 16KB]; osm union
    ushort_t* stage = (ushort_t*)shraw;
    float*    osm   = (float*)shraw;                           // [4][64][33] after main loop

    const int tid  = threadIdx.x;
    const int lane = tid & 63;
    const int wave = tid >> 6;
    const int lo5  = lane & 31;
    const int hi   = lane >> 5;
    const int qs   = wave >> 1;          // q sub-tile (0,1)
    const int sub  = wave & 1;           // kv sub within each 64-group (0,1)

    const int bid  = blockIdx.x;
    const int wg   = (bid & 7) * 128 + (bid >> 3);  // XCD-contiguous (4 heads/XCD)
    const int head = wg >> 5;
    const int q0b  = (wg & 31) * QB;

    const float*    Qh = gQ   + (size_t)head * SS * DD;
    const ushort_t* Kh = Kbf  + (size_t)head * SS * DD;
    const ushort_t* Vh = Vtbf + (size_t)head * DD * SS;   // [d][kv]
    float* Oh = gO + (size_t)head * SS * DD;
    float* Ph = gP + (size_t)head * SS * SS;

    const float SCALE = 0.125f * 1.44269504088896340736f; // (1/sqrt(64)) * log2(e)

    // ---- Q B-fragments from fp32 global (scale+log2e folded) ----
    const int qrow = q0b + qs * 32 + lo5;
    bf16x8 qf[4];
#pragma unroll
    for (int ks = 0; ks < 4; ++ks) {
        const float* qp = Qh + (size_t)qrow * DD + ks * 16 + hi * 8;
        f32x4 a = *(const f32x4*)(qp);
        f32x4 b = *(const f32x4*)(qp + 4);
        bf16x8 o;
#pragma unroll
        for (int j = 0; j < 4; ++j) o[j] = (short)f2bf(a[j] * SCALE);
#pragma unroll
        for (int j = 0; j < 4; ++j) o[4 + j] = (short)f2bf(b[j] * SCALE);
        qf[ks] = o;
    }

    // ---- staging addresses (source pre-swizzled, LDS dest linear; involutions match reads) ----
    // K tile [128 rows][64 cols bf16]: row = W*8+lgrp (W=wave*4+j), 8 chunks of 16B, chk^=(row&7)
    const int lgrp = lane >> 3;              // 0..7
    const int kchk = (lane & 7) ^ lgrp;      // involution
    const ushort_t* srcK[4];
    // V^T tile [64 rows d][128 cols kv]: row d = W2*4+(lane>>4) (W2=wave*4+j), 16 chunks, chk^=(d&7)
    const ushort_t* srcV[4];
#pragma unroll
    for (int j = 0; j < 4; ++j) {
        int W = wave * 4 + j;
        srcK[j] = Kh + (size_t)(W * 8 + lgrp) * DD + kchk * 8;
        int d = W * 4 + (lane >> 4);
        int vchk = (lane & 15) ^ (d & 7);
        srcV[j] = Vh + (size_t)d * SS + vchk * 8;
    }

    // ================= PASS A: denominator (max-free), KVB=128 =================
#pragma unroll
    for (int j = 0; j < 4; ++j) GLL16(srcK[j], stage + (wave * 4 + j) * 512);
    __syncthreads();

    float ls0 = 0.f, ls1 = 0.f;
    for (int t = 0; t < NT; ++t) {
        const int buf = t & 1;
        if (t + 1 < NT) {
#pragma unroll
            for (int j = 0; j < 4; ++j)
                GLL16(srcK[j] + (size_t)(t + 1) * KVB * DD,
                      stage + (buf ^ 1) * 16384 + (wave * 4 + j) * 512);
        }
        const ushort_t* Ksb = stage + buf * 16384;
#pragma unroll
        for (int g64 = 0; g64 < 2; ++g64) {
            const int kvl = g64 * 64 + sub * 32 + lo5;
            f32x16 acc = zero16();
#pragma unroll
            for (int ks = 0; ks < 4; ++ks) {
                bf16x8 kf = *(const bf16x8*)(Ksb + kvl * 64 + ((((ks * 2) + hi) ^ (kvl & 7)) << 3));
                acc = __builtin_amdgcn_mfma_f32_32x32x16_bf16(kf, qf[ks], acc, 0, 0, 0);
            }
#pragma unroll
            for (int r = 0; r < 16; r += 2) {
                ls0 += __builtin_exp2f(acc[r]);
                ls1 += __builtin_exp2f(acc[r + 1]);
            }
        }
        __syncthreads();
    }
    float lsum = ls0 + ls1;
    lsum += __shfl_xor(lsum, 32);
    lsm[wave][lo5] = lsum;
    __syncthreads();
    const float rinv = 1.0f / (lsm[qs * 2][lo5] + lsm[qs * 2 + 1][lo5]);

    // ================= PASS B: scores, P write, PV; KVB=128 =================
    f32x16 o0 = zero16(), o1 = zero16();
    float* prow_base = Ph + (size_t)qrow * SS;

#pragma unroll
    for (int j = 0; j < 4; ++j) {
        GLL16(srcK[j], stage + (wave * 4 + j) * 512);
        GLL16(srcV[j], stage + 8192 + (wave * 4 + j) * 512);
    }
    __syncthreads();

    for (int t = 0; t < NT; ++t) {
        const int buf = t & 1;
        if (t + 1 < NT) {
#pragma unroll
            for (int j = 0; j < 4; ++j) {
                GLL16(srcK[j] + (size_t)(t + 1) * KVB * DD,
                      stage + (buf ^ 1) * 16384 + (wave * 4 + j) * 512);
                GLL16(srcV[j] + (size_t)(t + 1) * KVB,
                      stage + (buf ^ 1) * 16384 + 8192 + (wave * 4 + j) * 512);
            }
        }
        const ushort_t* Ksb = stage + buf * 16384;
        const ushort_t* Vtb = Ksb + 8192;                 // V rows are 128 ushorts (256B, 16 chunks)

#pragma unroll
        for (int g64 = 0; g64 < 2; ++g64) {
            const int kvl = g64 * 64 + sub * 32 + lo5;
            f32x16 acc = zero16();
#pragma unroll
            for (int ks = 0; ks < 4; ++ks) {
                bf16x8 kf = *(const bf16x8*)(Ksb + kvl * 64 + ((((ks * 2) + hi) ^ (kvl & 7)) << 3));
                acc = __builtin_amdgcn_mfma_f32_32x32x16_bf16(kf, qf[ks], acc, 0, 0, 0);
            }
            float pr[16];
#pragma unroll
            for (int r = 0; r < 16; ++r) pr[r] = __builtin_exp2f(acc[r]);

            // normalized P store
            float* prow = prow_base + t * KVB + g64 * 64 + sub * 32;
#pragma unroll
            for (int g = 0; g < 4; ++g) {
                f32x4 st = { pr[4*g+0] * rinv, pr[4*g+1] * rinv, pr[4*g+2] * rinv, pr[4*g+3] * rinv };
                *(f32x4*)(prow + g * 8 + hi * 4) = st;
            }

            // rounding bf16 pack + half-wave exchange (R2-proven)
            unsigned u[8];
#pragma unroll
            for (int j = 0; j < 8; ++j)
                u[j] = (unsigned)f2bf(pr[2*j]) | ((unsigned)f2bf(pr[2*j+1]) << 16);
            unsigned s0 = __shfl_xor(u[0], 32), s1 = __shfl_xor(u[1], 32);
            unsigned s2 = __shfl_xor(u[2], 32), s3 = __shfl_xor(u[3], 32);
            unsigned s4 = __shfl_xor(u[4], 32), s5 = __shfl_xor(u[5], 32);
            unsigned s6 = __shfl_xor(u[6], 32), s7 = __shfl_xor(u[7], 32);
            PFrag pf0, pf1;
            pf0.w[0] = hi ? s2 : u[0];  pf0.w[1] = hi ? s3 : u[1];
            pf0.w[2] = hi ? u[2] : s0;  pf0.w[3] = hi ? u[3] : s1;
            pf1.w[0] = hi ? s6 : u[4];  pf1.w[1] = hi ? s7 : u[5];
            pf1.w[2] = hi ? u[6] : s4;  pf1.w[3] = hi ? u[7] : s5;

            // PV: O^T[64d][32q] += V^T * P^T  (V row 16 chunks; chunk = g64*8 + sub*4 + k + hi, low3 ^ row&7)
#pragma unroll
            for (int dt = 0; dt < 2; ++dt) {
                int drow = dt * 32 + lo5;
                int c0 = (g64 << 3) + (((sub * 4) + 0 + hi) ^ (drow & 7));
                int c1 = (g64 << 3) + (((sub * 4) + 2 + hi) ^ (drow & 7));
                bf16x8 vf0 = *(const bf16x8*)(Vtb + drow * 128 + (c0 << 3));
                bf16x8 vf1 = *(const bf16x8*)(Vtb + drow * 128 + (c1 << 3));
                f32x16& od = dt ? o1 : o0;
                od = __builtin_amdgcn_mfma_f32_32x32x16_bf16(vf0, pf0.v, od, 0, 0, 0);
                od = __builtin_amdgcn_mfma_f32_32x32x16_bf16(vf1, pf1.v, od, 0, 0, 0);
            }
        }
        __syncthreads();
    }

    // ================= epilogue: 2-way O reduce through reused LDS =================
#pragma unroll
    for (int dt = 0; dt < 2; ++dt) {
        const f32x16& od = dt ? o1 : o0;
#pragma unroll
        for (int g = 0; g < 4; ++g) {
#pragma unroll
            for (int j = 0; j < 4; ++j) {
                int d = dt * 32 + g * 8 + hi * 4 + j;
                osm[(wave * 64 + d) * 33 + lo5] = od[4 * g + j];
            }
        }
    }
    __syncthreads();
    {
        const int p  = tid >> 7;            // q sub-tile
        const int q  = (tid >> 2) & 31;
        const int d0 = (tid & 3) * 16;
        const float rq = 1.0f / (lsm[2 * p][q] + lsm[2 * p + 1][q]);
        float* op = Oh + (size_t)(q0b + p * 32 + q) * DD + d0;
#pragma unroll
        for (int v4 = 0; v4 < 4; ++v4) {
            f32x4 st;
#pragma unroll
            for (int j = 0; j < 4; ++j) {
                int d = d0 + v4 * 4 + j;
                st[j] = (osm[((2 * p) * 64 + d) * 33 + q] +
                         osm[((2 * p + 1) * 64 + d) * 33 + q]) * rq;
            }
            *(f32x4*)(op + v4 * 4) = st;
        }
    }
}

// ================= fallback (no-ws path) =================
__global__ __launch_bounds__(256, 2)
void attn_fused(const float* __restrict__ gQ, const float* __restrict__ gK,
                const float* __restrict__ gV, float* __restrict__ gO,
                float* __restrict__ gP)
{
    __shared__ unsigned short Qs[128 * DD];
    __shared__ unsigned short Ks[64 * DD];
    __shared__ unsigned short Vt[DD * 64];

    const int tid  = threadIdx.x;
    const int lane = tid & 63;
    const int wave = tid >> 6;
    const int lo5  = lane & 31;
    const int hi   = lane >> 5;

    const int head = blockIdx.x >> 4;
    const int q0b  = (blockIdx.x & 15) * 128;

    const float* Qh = gQ + (size_t)head * SS * DD;
    const float* Kh = gK + (size_t)head * SS * DD;
    const float* Vh = gV + (size_t)head * SS * DD;
    float* Oh = gO + (size_t)head * SS * DD;
    float* Ph = gP + (size_t)head * SS * SS;

    const float SCALE = 0.125f * 1.44269504088896340736f;

#pragma unroll
    for (int it = 0; it < 8; ++it) {
        int m = it * 256 + tid;
        int q = m >> 4, d4 = m & 15;
        f32x4 v = *(const f32x4*)(Qh + (size_t)(q0b + q) * DD + d4 * 4);
        unsigned a = (unsigned)f2bf(v.x * SCALE) | ((unsigned)f2bf(v.y * SCALE) << 16);
        unsigned b = (unsigned)f2bf(v.z * SCALE) | ((unsigned)f2bf(v.w * SCALE) << 16);
        u32x2 w; w.x = a; w.y = b;
        *(u32x2*)(Qs + q * 64 + d4 * 4) = w;
    }
    __syncthreads();

    const int qrow = wave * 32 + lo5;
    bf16x8 qf[4];
#pragma unroll
    for (int ks = 0; ks < 4; ++ks)
        qf[ks] = *(const bf16x8*)(Qs + qrow * 64 + ks * 16 + hi * 8);

    auto stageK = [&](int kv0) {
#pragma unroll
        for (int it = 0; it < 4; ++it) {
            int m = it * 256 + tid;
            int kv = m >> 4, d4 = m & 15;
            f32x4 v = *(const f32x4*)(Kh + (size_t)(kv0 + kv) * DD + d4 * 4);
            unsigned a = (unsigned)f2bf(v.x) | ((unsigned)f2bf(v.y) << 16);
            unsigned b = (unsigned)f2bf(v.z) | ((unsigned)f2bf(v.w) << 16);
            int c16 = (d4 >> 1) ^ (kv & 7);
            u32x2 w; w.x = a; w.y = b;
            *(u32x2*)(Ks + kv * 64 + c16 * 8 + (d4 & 1) * 4) = w;
        }
    };
    auto stageV = [&](int kv0) {
#pragma unroll
        for (int it = 0; it < 2; ++it) {
            int m = it * 256 + tid;
            int kv2 = m >> 4, d4 = m & 15;
            const float* p0 = Vh + (size_t)(kv0 + kv2 * 2) * DD + d4 * 4;
            f32x4 v0 = *(const f32x4*)(p0);
            f32x4 v1 = *(const f32x4*)(p0 + DD);
#pragma unroll
            for (int c = 0; c < 4; ++c) {
                int d = d4 * 4 + c;
                unsigned u = (unsigned)f2bf(v0[c]) | ((unsigned)f2bf(v1[c]) << 16);
                int c16 = (kv2 >> 2) ^ (d & 7);
                *(unsigned*)(Vt + d * 64 + c16 * 8 + (kv2 & 3) * 2) = u;
            }
        }
    };

    float m_run = -1e30f, l_run = 0.f;
    for (int kv0 = 0; kv0 < SS; kv0 += 64) {
        __syncthreads();
        stageK(kv0);
        __syncthreads();
#pragma unroll
        for (int sub = 0; sub < 2; ++sub) {
            f32x16 acc = zero16();
            int kvl = sub * 32 + lo5;
#pragma unroll
            for (int ks = 0; ks < 4; ++ks) {
                bf16x8 kf = *(const bf16x8*)(Ks + kvl * 64 + ((((ks * 2) + hi) ^ (kvl & 7)) << 3));
                acc = __builtin_amdgcn_mfma_f32_32x32x16_bf16(kf, qf[ks], acc, 0, 0, 0);
            }
            float tm = acc[0];
#pragma unroll
            for (int r = 1; r < 16; ++r) tm = fmaxf(tm, acc[r]);
            float mn = fmaxf(m_run, tm);
            float sum = 0.f;
#pragma unroll
            for (int r = 0; r < 16; ++r) sum += __builtin_exp2f(acc[r] - mn);
            l_run = l_run * __builtin_exp2f(m_run - mn) + sum;
            m_run = mn;
        }
    }
    {
        float mo = __shfl_xor(m_run, 32);
        float mf = fmaxf(m_run, mo);
        float la = l_run * __builtin_exp2f(m_run - mf);
        float lb = __shfl_xor(la, 32);
        l_run = la + lb;
        m_run = mf;
    }
    const float rinv = 1.0f / l_run;

    f32x16 o0 = zero16(), o1 = zero16();
    const int qg = q0b + wave * 32 + lo5;
    float* prow_base = Ph + (size_t)qg * SS;

    for (int kv0 = 0; kv0 < SS; kv0 += 64) {
        __syncthreads();
        stageK(kv0);
        stageV(kv0);
        __syncthreads();
#pragma unroll
        for (int sub = 0; sub < 2; ++sub) {
            f32x16 acc = zero16();
            int kvl = sub * 32 + lo5;
#pragma unroll
            for (int ks = 0; ks < 4; ++ks) {
                bf16x8 kf = *(const bf16x8*)(Ks + kvl * 64 + ((((ks * 2) + hi) ^ (kvl & 7)) << 3));
                acc = __builtin_amdgcn_mfma_f32_32x32x16_bf16(kf, qf[ks], acc, 0, 0, 0);
            }
            float pr[16];
#pragma unroll
            for (int r = 0; r < 16; ++r) pr[r] = __builtin_exp2f(acc[r] - m_run);

            float* prow = prow_base + kv0 + sub * 32;
#pragma unroll
            for (int g = 0; g < 4; ++g) {
                f32x4 st = { pr[4*g+0] * rinv, pr[4*g+1] * rinv, pr[4*g+2] * rinv, pr[4*g+3] * rinv };
                *(f32x4*)(prow + g * 8 + hi * 4) = st;
            }

            unsigned u[8];
#pragma unroll
            for (int j = 0; j < 8; ++j)
                u[j] = (unsigned)f2bf(pr[2*j]) | ((unsigned)f2bf(pr[2*j+1]) << 16);

            unsigned s0 = __shfl_xor(u[0], 32), s1 = __shfl_xor(u[1], 32);
            unsigned s2 = __shfl_xor(u[2], 32), s3 = __shfl_xor(u[3], 32);
            unsigned s4 = __shfl_xor(u[4], 32), s5 = __shfl_xor(u[5], 32);
            unsigned s6 = __shfl_xor(u[6], 32), s7 = __shfl_xor(u[7], 32);
            PFrag pf0, pf1;
            pf0.w[0] = hi ? s2 : u[0];  pf0.w[1] = hi ? s3 : u[1];
            pf0.w[2] = hi ? u[2] : s0;  pf0.w[3] = hi ? u[3] : s1;
            pf1.w[0] = hi ? s6 : u[4];  pf1.w[1] = hi ? s7 : u[5];
            pf1.w[2] = hi ? u[6] : s4;  pf1.w[3] = hi ? u[7] : s5;

#pragma unroll
            for (int dt = 0; dt < 2; ++dt) {
                int drow = dt * 32 + lo5;
                int c0 = ((sub * 4) + 0 + hi) ^ (drow & 7);
                int c1 = ((sub * 4) + 2 + hi) ^ (drow & 7);
                bf16x8 vf0 = *(const bf16x8*)(Vt + drow * 64 + (c0 << 3));
                bf16x8 vf1 = *(const bf16x8*)(Vt + drow * 64 + (c1 << 3));
                f32x16& od = dt ? o1 : o0;
                od = __builtin_amdgcn_mfma_f32_32x32x16_bf16(vf0, pf0.v, od, 0, 0, 0);
                od = __builtin_amdgcn_mfma_f32_32x32x16_bf16(vf1, pf1.v, od, 0, 0, 0);
            }
        }
    }

    float* orow = Oh + (size_t)qg * DD;
#pragma unroll
    for (int dt = 0; dt < 2; ++dt) {
        const f32x16& od = dt ? o1 : o0;
#pragma unroll
        for (int g = 0; g < 4; ++g) {
            f32x4 st = { od[4*g+0] * rinv, od[4*g+1] * rinv, od[4*g+2] * rinv, od[4*g+3] * rinv };
            *(f32x4*)(orow + dt * 32 + g * 8 + hi * 4) = st;
        }
    }
}

extern "C" void kernel_launch(void* const* d_in, const int* in_sizes, int n_in,
                              void* d_out, int out_size, void* d_ws, size_t ws_size,
                              hipStream_t stream) {
    const float* Q = (const float*)d_in[0];
    const float* K = (const float*)d_in[1];
    const float* V = (const float*)d_in[2];
    float* O = (float*)d_out;
    float* P = O + (size_t)2 * 16 * SS * DD;

    const size_t HD = (size_t)32 * SS * DD;           // elems per tensor
    const size_t need = 2 * HD * sizeof(ushort_t);    // K bf16 + V^T bf16 ≈ 16.8 MB

    if (ws_size >= need) {
        ushort_t* Kbf  = (ushort_t*)d_ws;
        ushort_t* Vtbf = Kbf + HD;
        hipLaunchKernelGGL(prep, dim3(3072), dim3(256), 0, stream, K, V, Kbf, Vtbf);
        hipLaunchKernelGGL(attn_main9, dim3(1024), dim3(256), 0, stream, Q, Kbf, Vtbf, O, P);
    } else {
        hipLaunchKernelGGL(attn_fused, dim3(512), dim3(256), 0, stream, Q, K, V, O, P);
    }
}